// Round 13
// baseline (1452.270 us; speedup 1.0000x reference)
//
#include <hip/hip_runtime.h>
#include <cstdint>
#include <cstddef>

// Problem constants
#define NB    8192      // batch
#define NP    4849      // params per item
#define NW    48        // target net width
#define NCH   38        // ceil(NP/128)
#define GY    128       // gemm grid y; each block does 1 M-tile

// Tiled intermediate layout: addr(i, rp) = ((rp>>7)*NB + i)*128 + (rp&127)
typedef __attribute__((ext_vector_type(8))) _Float16 f16x8;
typedef __attribute__((ext_vector_type(4))) float f32x4;
typedef __attribute__((ext_vector_type(2))) float f32x2;

__device__ __forceinline__ const float* pptr(const float* Pp, int i, int rp) {
  return Pp + ((size_t)(rp >> 7) * NB + i) * 128 + (rp & 127);
}

__device__ __forceinline__ int invperm(int rp) {
  if (rp >= 96 && rp < 2400) {
    int t = rp - 96; int kb = t / 192; int rem = t - kb * 192;
    return 96 + (rem >> 2) * 48 + (kb * 4 + (rem & 3));
  }
  if (rp >= 2448 && rp < 4752) {
    int t = rp - 2448; int kb = t / 192; int rem = t - kb * 192;
    return 2448 + (rem >> 2) * 48 + (kb * 4 + (rem & 3));
  }
  return rp;
}

// ---------------------------------------------------------------------------
// Kernel 1 (R24): split-fp16 MFMA GEMM, R21 store path (R23's LDS epilogue
// was neutral -> dropped), GY 64 -> 128: R18's latency-hiding lever extended
// (4864 blocks, 1 mtile each; cold counters showed nothing busy -> more
// blocks = more overlap of prologue load chains and stores).
// ---------------------------------------------------------------------------
__global__ __launch_bounds__(256, 2) void hyper_gemm(
    const float* __restrict__ x, const float* __restrict__ c,
    const float* __restrict__ hw1, const float* __restrict__ hb1,
    const float* __restrict__ hw2, const float* __restrict__ hb2,
    float* __restrict__ Pp)
{
  const int t    = threadIdx.x;
  const int lane = t & 63;
  const int wv   = t >> 6;
  const int m16  = lane & 15;
  const int q    = lane >> 4;
  const int rp0  = blockIdx.x * 128;

  const float* wr[2];
  float bias[2];
  #pragma unroll
  for (int nt = 0; nt < 2; ++nt) {
    int rp = rp0 + wv * 32 + nt * 16 + m16;
    int r  = (rp < NP) ? invperm(rp) : 0;
    wr[nt]   = hw2 + (size_t)r * 96;
    bias[nt] = (rp < NP) ? hb2[r] : 0.f;
  }

  f16x8 bh[3][2], bl[3][2];
  #pragma unroll
  for (int ch = 0; ch < 3; ++ch) {
    const int k0 = ch * 32 + q * 8;
    #pragma unroll
    for (int nt = 0; nt < 2; ++nt) {
      float4 f0 = *(const float4*)(wr[nt] + k0);
      float4 f1 = *(const float4*)(wr[nt] + k0 + 4);
      float fv[8] = {f0.x,f0.y,f0.z,f0.w,f1.x,f1.y,f1.z,f1.w};
      #pragma unroll
      for (int e = 0; e < 8; ++e) {
        _Float16 hi = (_Float16)fv[e];
        float r = fv[e] - (float)hi;
        bh[ch][nt][e] = hi;
        bl[ch][nt][e] = (_Float16)r;
      }
    }
  }

  float* cbase = Pp + (size_t)blockIdx.x * NB * 128;

  for (int mtile = blockIdx.y; mtile < 128; mtile += GY) {
    const int i0 = mtile * 64;

    float xv[4], cv[4];
    #pragma unroll
    for (int mt = 0; mt < 4; ++mt) {
      int i = i0 + mt * 16 + m16;
      xv[mt] = x[i]; cv[mt] = c[i];
    }

    f32x4 acc[4][2];
    #pragma unroll
    for (int mt = 0; mt < 4; ++mt)
      #pragma unroll
      for (int nt = 0; nt < 2; ++nt)
        acc[mt][nt] = (f32x4){0.f, 0.f, 0.f, 0.f};

    #pragma unroll
    for (int ch = 0; ch < 3; ++ch) {
      const int k0 = ch * 32 + q * 8;

      float4 A0 = *(const float4*)(hw1 + 2 * k0);
      float4 A1 = *(const float4*)(hw1 + 2 * k0 + 4);
      float4 A2 = *(const float4*)(hw1 + 2 * k0 + 8);
      float4 A3 = *(const float4*)(hw1 + 2 * k0 + 12);
      float4 B0 = *(const float4*)(hb1 + k0);
      float4 B1 = *(const float4*)(hb1 + k0 + 4);
      float w0k[8] = {A0.x,A0.z,A1.x,A1.z,A2.x,A2.z,A3.x,A3.z};
      float w1k[8] = {A0.y,A0.w,A1.y,A1.w,A2.y,A2.w,A3.y,A3.w};
      float bk[8]  = {B0.x,B0.y,B0.z,B0.w,B1.x,B1.y,B1.z,B1.w};

      f16x8 ah[4], al[4];
      #pragma unroll
      for (int mt = 0; mt < 4; ++mt) {
        #pragma unroll
        for (int j = 0; j < 8; ++j) {
          float h = fmaf(xv[mt], w0k[j], fmaf(cv[mt], w1k[j], bk[j]));
          h = h > 0.f ? h : 0.f;
          _Float16 hi = (_Float16)h;
          float r = h - (float)hi;
          ah[mt][j] = hi;
          al[mt][j] = (_Float16)r;
        }
      }

      #pragma unroll
      for (int mt = 0; mt < 4; ++mt)
        #pragma unroll
        for (int nt = 0; nt < 2; ++nt) {
          acc[mt][nt] = __builtin_amdgcn_mfma_f32_16x16x32_f16(al[mt], bl[ch][nt], acc[mt][nt], 0, 0, 0);
          acc[mt][nt] = __builtin_amdgcn_mfma_f32_16x16x32_f16(ah[mt], bl[ch][nt], acc[mt][nt], 0, 0, 0);
          acc[mt][nt] = __builtin_amdgcn_mfma_f32_16x16x32_f16(al[mt], bh[ch][nt], acc[mt][nt], 0, 0, 0);
          acc[mt][nt] = __builtin_amdgcn_mfma_f32_16x16x32_f16(ah[mt], bh[ch][nt], acc[mt][nt], 0, 0, 0);
        }
    }

    #pragma unroll
    for (int nt = 0; nt < 2; ++nt) {
      int off = wv * 32 + nt * 16 + m16;
      if (rp0 + off < NP) {
        #pragma unroll
        for (int mt = 0; mt < 4; ++mt)
          #pragma unroll
          for (int r = 0; r < 4; ++r) {
            int i = i0 + mt * 16 + q * 4 + r;
            cbase[(size_t)i * 128 + off] = acc[mt][nt][r] + bias[nt];
          }
      }
    }
  }
}

// ---------------------------------------------------------------------------
// Kernel 2 (R24 = R21 body + __launch_bounds__(64,4)).
// R21 measured: VGPR 116, Occupancy ~19% (~6 waves/CU), DS pipe ~80% of its
// floor, VALUBusy 52%. The body FITS a 128-reg cap (unlike R13's ~150-reg
// body that spilled under (64,4)) -> declaring 4 waves/EU should raise
// residency toward 12+ waves/CU and drive the DS pipe to saturation.
// Watch: VGPR must stay <=128 with FETCH ~78 MB (FETCH in GBs = spill =
// invalid experiment).
// ---------------------------------------------------------------------------

// x += dpp(x) with add-identity for invalid/masked lanes (LLVM reduce pattern)
#define DPP_ADD(x, ctrl, rmask)                                               \
  (x) += __int_as_float(__builtin_amdgcn_update_dpp(                          \
      0, __float_as_int(x), (ctrl), (rmask), 0xf, false))

__global__ __launch_bounds__(64, 4) void adam_inner(
    const float* __restrict__ Pp, float* __restrict__ out)
{
  __shared__ __align__(16) float hd[2][96];   // [buf][h(48)|dh(48)]

  const int lane = threadIdx.x;
  const int i    = blockIdx.x;
  const bool act = lane < NW;

  float* buf0 = &hd[0][0];
  float* buf1 = &hd[1][0];

  float w0  = act ? *pptr(Pp, i, lane)        : 0.f;
  float b0  = act ? *pptr(Pp, i, 48 + lane)   : 0.f;
  float b1v = act ? *pptr(Pp, i, 2400 + lane) : 0.f;
  float b2v = act ? *pptr(Pp, i, 4752 + lane) : 0.f;
  float w3  = act ? *pptr(Pp, i, 4800 + lane) : 0.f;

  f32x2 w1p[24], w2p[24];
  #pragma unroll
  for (int kb = 0; kb < 12; ++kb) {
    float4 q1 = *(const float4*)pptr(Pp, i, 96 + kb * 192 + lane * 4);
    w1p[2 * kb]     = (f32x2){q1.x, q1.y};
    w1p[2 * kb + 1] = (f32x2){q1.z, q1.w};
    float4 q2 = *(const float4*)pptr(Pp, i, 2448 + kb * 192 + lane * 4);
    w2p[2 * kb]     = (f32x2){q2.x, q2.y};
    w2p[2 * kb + 1] = (f32x2){q2.z, q2.w};
  }

  float y = 0.f, m = 0.f, v = 0.f;
  float b1t = 1.f, b2t = 1.f;

  #pragma unroll 1
  for (int t = 0; t < 20; ++t) {
    // ---- layer 0 (scalar input): lane j computes unit j ----
    float z  = fmaf(w0, y, b0);
    float s  = __builtin_amdgcn_rcpf(1.f + __expf(-z));
    float h  = z * s;
    float dh = fmaf(z * s, 1.f - s, s) * w0;
    if (act) { buf0[lane] = h; buf0[48 + lane] = dh; }

    // ---- layer 1: exec-masked broadcast prefetch, packed chains ----
    float4 ph[12], pd[12];
    if (act) {
      #pragma unroll
      for (int kk = 0; kk < 12; ++kk) {
        ph[kk] = *(const float4*)(buf0 + 4 * kk);
        pd[kk] = *(const float4*)(buf0 + 48 + 4 * kk);
      }
    }
    {
      f32x2 zz[4] = {(f32x2){b1v, 0.f}, (f32x2){0.f, 0.f},
                     (f32x2){0.f, 0.f}, (f32x2){0.f, 0.f}};
      f32x2 dd[4] = {(f32x2){0.f, 0.f}, (f32x2){0.f, 0.f},
                     (f32x2){0.f, 0.f}, (f32x2){0.f, 0.f}};
      #pragma unroll
      for (int kk = 0; kk < 12; ++kk) {
        int c0 = (2 * kk) & 3, c1 = (2 * kk + 1) & 3;
        zz[c0] = __builtin_elementwise_fma(w1p[2 * kk],     (f32x2){ph[kk].x, ph[kk].y}, zz[c0]);
        zz[c1] = __builtin_elementwise_fma(w1p[2 * kk + 1], (f32x2){ph[kk].z, ph[kk].w}, zz[c1]);
        dd[c0] = __builtin_elementwise_fma(w1p[2 * kk],     (f32x2){pd[kk].x, pd[kk].y}, dd[c0]);
        dd[c1] = __builtin_elementwise_fma(w1p[2 * kk + 1], (f32x2){pd[kk].z, pd[kk].w}, dd[c1]);
      }
      f32x2 zs = (zz[0] + zz[1]) + (zz[2] + zz[3]);
      f32x2 ds = (dd[0] + dd[1]) + (dd[2] + dd[3]);
      float z1  = zs.x + zs.y;
      float dz1 = ds.x + ds.y;

      s  = __builtin_amdgcn_rcpf(1.f + __expf(-z1));
      h  = z1 * s;
      dh = fmaf(h, 1.f - s, s) * dz1;
    }
    if (act) { buf1[lane] = h; buf1[48 + lane] = dh; }

    // ---- layer 2 ----
    if (act) {
      #pragma unroll
      for (int kk = 0; kk < 12; ++kk) {
        ph[kk] = *(const float4*)(buf1 + 4 * kk);
        pd[kk] = *(const float4*)(buf1 + 48 + 4 * kk);
      }
    }
    {
      f32x2 zz[4] = {(f32x2){b2v, 0.f}, (f32x2){0.f, 0.f},
                     (f32x2){0.f, 0.f}, (f32x2){0.f, 0.f}};
      f32x2 dd[4] = {(f32x2){0.f, 0.f}, (f32x2){0.f, 0.f},
                     (f32x2){0.f, 0.f}, (f32x2){0.f, 0.f}};
      #pragma unroll
      for (int kk = 0; kk < 12; ++kk) {
        int c0 = (2 * kk) & 3, c1 = (2 * kk + 1) & 3;
        zz[c0] = __builtin_elementwise_fma(w2p[2 * kk],     (f32x2){ph[kk].x, ph[kk].y}, zz[c0]);
        zz[c1] = __builtin_elementwise_fma(w2p[2 * kk + 1], (f32x2){ph[kk].z, ph[kk].w}, zz[c1]);
        dd[c0] = __builtin_elementwise_fma(w2p[2 * kk],     (f32x2){pd[kk].x, pd[kk].y}, dd[c0]);
        dd[c1] = __builtin_elementwise_fma(w2p[2 * kk + 1], (f32x2){pd[kk].z, pd[kk].w}, dd[c1]);
      }
      f32x2 zs = (zz[0] + zz[1]) + (zz[2] + zz[3]);
      f32x2 ds = (dd[0] + dd[1]) + (dd[2] + dd[3]);
      float z2  = zs.x + zs.y;
      float dz2 = ds.x + ds.y;

      s  = __builtin_amdgcn_rcpf(1.f + __expf(-z2));
      dh = fmaf(z2 * s, 1.f - s, s) * dz2;
    }

    // ---- g = w3 . dh3 : DPP reduction (VALU pipe, no DS ops) ----
    float r = act ? w3 * dh : 0.f;
    DPP_ADD(r, 0x111, 0xf);   // row_shr:1
    DPP_ADD(r, 0x112, 0xf);   // row_shr:2
    DPP_ADD(r, 0x114, 0xf);   // row_shr:4
    DPP_ADD(r, 0x118, 0xf);   // row_shr:8  -> lane15 of each row = row sum
    DPP_ADD(r, 0x142, 0xa);   // row_bcast:15 into rows 1,3
    DPP_ADD(r, 0x143, 0xc);   // row_bcast:31 into rows 2,3 -> lane63 = total
    float g = __int_as_float(__builtin_amdgcn_readlane(__float_as_int(r), 63));

    // ---- Adam update (replicated per lane) ----
    m = fmaf(0.9f,   m, 0.1f   * g);
    v = fmaf(0.999f, v, 0.001f * g * g);
    b1t *= 0.9f; b2t *= 0.999f;
    float mh  = m * __builtin_amdgcn_rcpf(1.f - b1t);
    float vh  = v * __builtin_amdgcn_rcpf(1.f - b2t);
    float den = __builtin_amdgcn_sqrtf(vh) + 1e-8f;
    y -= 0.1f * mh * __builtin_amdgcn_rcpf(den);
  }

  if (lane == 0) out[i] = y;
}

// ---------------------------------------------------------------------------
extern "C" void kernel_launch(void* const* d_in, const int* in_sizes, int n_in,
                              void* d_out, int out_size, void* d_ws, size_t ws_size,
                              hipStream_t stream) {
  const float* x   = (const float*)d_in[0];
  const float* c   = (const float*)d_in[1];
  const float* hw1 = (const float*)d_in[2];
  const float* hb1 = (const float*)d_in[3];
  const float* hw2 = (const float*)d_in[4];
  const float* hb2 = (const float*)d_in[5];
  float* Pp  = (float*)d_ws;   // NCH*NB*128*4 = 159,383,552 bytes
  float* out = (float*)d_out;

  dim3 gridB(NCH, GY);         // 38 x 128 blocks
  hyper_gemm<<<gridB, dim3(256), 0, stream>>>(x, c, hw1, hb1, hw2, hb2, Pp);
  adam_inner<<<dim3(8192), dim3(64), 0, stream>>>(Pp, out);
}

// Round 14
// 202.963 us; speedup vs baseline: 7.1553x; 7.1553x over previous
//
#include <hip/hip_runtime.h>
#include <cstdint>
#include <cstddef>

// Problem constants
#define NB    8192      // batch
#define NP    4849      // params per item
#define NW    48        // target net width
#define NCH   38        // ceil(NP/128)
#define GY    128       // gemm grid y; each block does 1 M-tile

// Tiled intermediate layout: addr(i, rp) = ((rp>>7)*NB + i)*128 + (rp&127)
typedef __attribute__((ext_vector_type(8))) _Float16 f16x8;
typedef __attribute__((ext_vector_type(4))) float f32x4;
typedef __attribute__((ext_vector_type(2))) float f32x2;

__device__ __forceinline__ const float* pptr(const float* Pp, int i, int rp) {
  return Pp + ((size_t)(rp >> 7) * NB + i) * 128 + (rp & 127);
}

__device__ __forceinline__ int invperm(int rp) {
  if (rp >= 96 && rp < 2400) {
    int t = rp - 96; int kb = t / 192; int rem = t - kb * 192;
    return 96 + (rem >> 2) * 48 + (kb * 4 + (rem & 3));
  }
  if (rp >= 2448 && rp < 4752) {
    int t = rp - 2448; int kb = t / 192; int rem = t - kb * 192;
    return 2448 + (rem >> 2) * 48 + (kb * 4 + (rem & 3));
  }
  return rp;
}

// ---------------------------------------------------------------------------
// Kernel 1 (R25): split-fp16 MFMA GEMM, R21 store path, GY=128 (the one
// untested-in-isolation knob; R24's GY=128 measurement was destroyed by the
// adam spill). Latency-bound kernel: more blocks = more overlap.
// ---------------------------------------------------------------------------
__global__ __launch_bounds__(256, 2) void hyper_gemm(
    const float* __restrict__ x, const float* __restrict__ c,
    const float* __restrict__ hw1, const float* __restrict__ hb1,
    const float* __restrict__ hw2, const float* __restrict__ hb2,
    float* __restrict__ Pp)
{
  const int t    = threadIdx.x;
  const int lane = t & 63;
  const int wv   = t >> 6;
  const int m16  = lane & 15;
  const int q    = lane >> 4;
  const int rp0  = blockIdx.x * 128;

  const float* wr[2];
  float bias[2];
  #pragma unroll
  for (int nt = 0; nt < 2; ++nt) {
    int rp = rp0 + wv * 32 + nt * 16 + m16;
    int r  = (rp < NP) ? invperm(rp) : 0;
    wr[nt]   = hw2 + (size_t)r * 96;
    bias[nt] = (rp < NP) ? hb2[r] : 0.f;
  }

  f16x8 bh[3][2], bl[3][2];
  #pragma unroll
  for (int ch = 0; ch < 3; ++ch) {
    const int k0 = ch * 32 + q * 8;
    #pragma unroll
    for (int nt = 0; nt < 2; ++nt) {
      float4 f0 = *(const float4*)(wr[nt] + k0);
      float4 f1 = *(const float4*)(wr[nt] + k0 + 4);
      float fv[8] = {f0.x,f0.y,f0.z,f0.w,f1.x,f1.y,f1.z,f1.w};
      #pragma unroll
      for (int e = 0; e < 8; ++e) {
        _Float16 hi = (_Float16)fv[e];
        float r = fv[e] - (float)hi;
        bh[ch][nt][e] = hi;
        bl[ch][nt][e] = (_Float16)r;
      }
    }
  }

  float* cbase = Pp + (size_t)blockIdx.x * NB * 128;

  for (int mtile = blockIdx.y; mtile < 128; mtile += GY) {
    const int i0 = mtile * 64;

    float xv[4], cv[4];
    #pragma unroll
    for (int mt = 0; mt < 4; ++mt) {
      int i = i0 + mt * 16 + m16;
      xv[mt] = x[i]; cv[mt] = c[i];
    }

    f32x4 acc[4][2];
    #pragma unroll
    for (int mt = 0; mt < 4; ++mt)
      #pragma unroll
      for (int nt = 0; nt < 2; ++nt)
        acc[mt][nt] = (f32x4){0.f, 0.f, 0.f, 0.f};

    #pragma unroll
    for (int ch = 0; ch < 3; ++ch) {
      const int k0 = ch * 32 + q * 8;

      float4 A0 = *(const float4*)(hw1 + 2 * k0);
      float4 A1 = *(const float4*)(hw1 + 2 * k0 + 4);
      float4 A2 = *(const float4*)(hw1 + 2 * k0 + 8);
      float4 A3 = *(const float4*)(hw1 + 2 * k0 + 12);
      float4 B0 = *(const float4*)(hb1 + k0);
      float4 B1 = *(const float4*)(hb1 + k0 + 4);
      float w0k[8] = {A0.x,A0.z,A1.x,A1.z,A2.x,A2.z,A3.x,A3.z};
      float w1k[8] = {A0.y,A0.w,A1.y,A1.w,A2.y,A2.w,A3.y,A3.w};
      float bk[8]  = {B0.x,B0.y,B0.z,B0.w,B1.x,B1.y,B1.z,B1.w};

      f16x8 ah[4], al[4];
      #pragma unroll
      for (int mt = 0; mt < 4; ++mt) {
        #pragma unroll
        for (int j = 0; j < 8; ++j) {
          float h = fmaf(xv[mt], w0k[j], fmaf(cv[mt], w1k[j], bk[j]));
          h = h > 0.f ? h : 0.f;
          _Float16 hi = (_Float16)h;
          float r = h - (float)hi;
          ah[mt][j] = hi;
          al[mt][j] = (_Float16)r;
        }
      }

      #pragma unroll
      for (int mt = 0; mt < 4; ++mt)
        #pragma unroll
        for (int nt = 0; nt < 2; ++nt) {
          acc[mt][nt] = __builtin_amdgcn_mfma_f32_16x16x32_f16(al[mt], bl[ch][nt], acc[mt][nt], 0, 0, 0);
          acc[mt][nt] = __builtin_amdgcn_mfma_f32_16x16x32_f16(ah[mt], bl[ch][nt], acc[mt][nt], 0, 0, 0);
          acc[mt][nt] = __builtin_amdgcn_mfma_f32_16x16x32_f16(al[mt], bh[ch][nt], acc[mt][nt], 0, 0, 0);
          acc[mt][nt] = __builtin_amdgcn_mfma_f32_16x16x32_f16(ah[mt], bh[ch][nt], acc[mt][nt], 0, 0, 0);
        }
    }

    #pragma unroll
    for (int nt = 0; nt < 2; ++nt) {
      int off = wv * 32 + nt * 16 + m16;
      if (rp0 + off < NP) {
        #pragma unroll
        for (int mt = 0; mt < 4; ++mt)
          #pragma unroll
          for (int r = 0; r < 4; ++r) {
            int i = i0 + mt * 16 + q * 4 + r;
            cbase[(size_t)i * 128 + off] = acc[mt][nt][r] + bias[nt];
          }
      }
    }
  }
}

// ---------------------------------------------------------------------------
// Kernel 2 (R25 = R21 VERBATIM, best measured: 98.5 us, absmax 0.023).
// LDS-broadcast-bandwidth bound at ~80% of the DS-pipe floor. Exec-masked
// b128 broadcasts + packed f32x2 chains, __launch_bounds__(64,2).
// DO NOT set min-waves>2 with 64-thread blocks: the allocator clamps VGPR
// to 64 and scratch-spills (R13, R24: FETCH 1-3 GB, 3-13x slowdown).
// Measured-dead alternatives: readlane transport (R17/R20), f16 h/dh (R19
// numerics: Adam step-1 = -LR*sign(g), tiny-g sign flips), 2-item/wave
// (R22 occupancy collapse), MFMA relayout (R15/R16 correctness).
// ---------------------------------------------------------------------------

// x += dpp(x) with add-identity for invalid/masked lanes (LLVM reduce pattern)
#define DPP_ADD(x, ctrl, rmask)                                               \
  (x) += __int_as_float(__builtin_amdgcn_update_dpp(                          \
      0, __float_as_int(x), (ctrl), (rmask), 0xf, false))

__global__ __launch_bounds__(64, 2) void adam_inner(
    const float* __restrict__ Pp, float* __restrict__ out)
{
  __shared__ __align__(16) float hd[2][96];   // [buf][h(48)|dh(48)]

  const int lane = threadIdx.x;
  const int i    = blockIdx.x;
  const bool act = lane < NW;

  float* buf0 = &hd[0][0];
  float* buf1 = &hd[1][0];

  float w0  = act ? *pptr(Pp, i, lane)        : 0.f;
  float b0  = act ? *pptr(Pp, i, 48 + lane)   : 0.f;
  float b1v = act ? *pptr(Pp, i, 2400 + lane) : 0.f;
  float b2v = act ? *pptr(Pp, i, 4752 + lane) : 0.f;
  float w3  = act ? *pptr(Pp, i, 4800 + lane) : 0.f;

  f32x2 w1p[24], w2p[24];
  #pragma unroll
  for (int kb = 0; kb < 12; ++kb) {
    float4 q1 = *(const float4*)pptr(Pp, i, 96 + kb * 192 + lane * 4);
    w1p[2 * kb]     = (f32x2){q1.x, q1.y};
    w1p[2 * kb + 1] = (f32x2){q1.z, q1.w};
    float4 q2 = *(const float4*)pptr(Pp, i, 2448 + kb * 192 + lane * 4);
    w2p[2 * kb]     = (f32x2){q2.x, q2.y};
    w2p[2 * kb + 1] = (f32x2){q2.z, q2.w};
  }

  float y = 0.f, m = 0.f, v = 0.f;
  float b1t = 1.f, b2t = 1.f;

  #pragma unroll 1
  for (int t = 0; t < 20; ++t) {
    // ---- layer 0 (scalar input): lane j computes unit j ----
    float z  = fmaf(w0, y, b0);
    float s  = __builtin_amdgcn_rcpf(1.f + __expf(-z));
    float h  = z * s;
    float dh = fmaf(z * s, 1.f - s, s) * w0;
    if (act) { buf0[lane] = h; buf0[48 + lane] = dh; }

    // ---- layer 1: exec-masked broadcast prefetch, packed chains ----
    float4 ph[12], pd[12];
    if (act) {
      #pragma unroll
      for (int kk = 0; kk < 12; ++kk) {
        ph[kk] = *(const float4*)(buf0 + 4 * kk);
        pd[kk] = *(const float4*)(buf0 + 48 + 4 * kk);
      }
    }
    {
      f32x2 zz[4] = {(f32x2){b1v, 0.f}, (f32x2){0.f, 0.f},
                     (f32x2){0.f, 0.f}, (f32x2){0.f, 0.f}};
      f32x2 dd[4] = {(f32x2){0.f, 0.f}, (f32x2){0.f, 0.f},
                     (f32x2){0.f, 0.f}, (f32x2){0.f, 0.f}};
      #pragma unroll
      for (int kk = 0; kk < 12; ++kk) {
        int c0 = (2 * kk) & 3, c1 = (2 * kk + 1) & 3;
        zz[c0] = __builtin_elementwise_fma(w1p[2 * kk],     (f32x2){ph[kk].x, ph[kk].y}, zz[c0]);
        zz[c1] = __builtin_elementwise_fma(w1p[2 * kk + 1], (f32x2){ph[kk].z, ph[kk].w}, zz[c1]);
        dd[c0] = __builtin_elementwise_fma(w1p[2 * kk],     (f32x2){pd[kk].x, pd[kk].y}, dd[c0]);
        dd[c1] = __builtin_elementwise_fma(w1p[2 * kk + 1], (f32x2){pd[kk].z, pd[kk].w}, dd[c1]);
      }
      f32x2 zs = (zz[0] + zz[1]) + (zz[2] + zz[3]);
      f32x2 ds = (dd[0] + dd[1]) + (dd[2] + dd[3]);
      float z1  = zs.x + zs.y;
      float dz1 = ds.x + ds.y;

      s  = __builtin_amdgcn_rcpf(1.f + __expf(-z1));
      h  = z1 * s;
      dh = fmaf(h, 1.f - s, s) * dz1;
    }
    if (act) { buf1[lane] = h; buf1[48 + lane] = dh; }

    // ---- layer 2 ----
    if (act) {
      #pragma unroll
      for (int kk = 0; kk < 12; ++kk) {
        ph[kk] = *(const float4*)(buf1 + 4 * kk);
        pd[kk] = *(const float4*)(buf1 + 48 + 4 * kk);
      }
    }
    {
      f32x2 zz[4] = {(f32x2){b2v, 0.f}, (f32x2){0.f, 0.f},
                     (f32x2){0.f, 0.f}, (f32x2){0.f, 0.f}};
      f32x2 dd[4] = {(f32x2){0.f, 0.f}, (f32x2){0.f, 0.f},
                     (f32x2){0.f, 0.f}, (f32x2){0.f, 0.f}};
      #pragma unroll
      for (int kk = 0; kk < 12; ++kk) {
        int c0 = (2 * kk) & 3, c1 = (2 * kk + 1) & 3;
        zz[c0] = __builtin_elementwise_fma(w2p[2 * kk],     (f32x2){ph[kk].x, ph[kk].y}, zz[c0]);
        zz[c1] = __builtin_elementwise_fma(w2p[2 * kk + 1], (f32x2){ph[kk].z, ph[kk].w}, zz[c1]);
        dd[c0] = __builtin_elementwise_fma(w2p[2 * kk],     (f32x2){pd[kk].x, pd[kk].y}, dd[c0]);
        dd[c1] = __builtin_elementwise_fma(w2p[2 * kk + 1], (f32x2){pd[kk].z, pd[kk].w}, dd[c1]);
      }
      f32x2 zs = (zz[0] + zz[1]) + (zz[2] + zz[3]);
      f32x2 ds = (dd[0] + dd[1]) + (dd[2] + dd[3]);
      float z2  = zs.x + zs.y;
      float dz2 = ds.x + ds.y;

      s  = __builtin_amdgcn_rcpf(1.f + __expf(-z2));
      dh = fmaf(z2 * s, 1.f - s, s) * dz2;
    }

    // ---- g = w3 . dh3 : DPP reduction (VALU pipe, no DS ops) ----
    float r = act ? w3 * dh : 0.f;
    DPP_ADD(r, 0x111, 0xf);   // row_shr:1
    DPP_ADD(r, 0x112, 0xf);   // row_shr:2
    DPP_ADD(r, 0x114, 0xf);   // row_shr:4
    DPP_ADD(r, 0x118, 0xf);   // row_shr:8  -> lane15 of each row = row sum
    DPP_ADD(r, 0x142, 0xa);   // row_bcast:15 into rows 1,3
    DPP_ADD(r, 0x143, 0xc);   // row_bcast:31 into rows 2,3 -> lane63 = total
    float g = __int_as_float(__builtin_amdgcn_readlane(__float_as_int(r), 63));

    // ---- Adam update (replicated per lane) ----
    m = fmaf(0.9f,   m, 0.1f   * g);
    v = fmaf(0.999f, v, 0.001f * g * g);
    b1t *= 0.9f; b2t *= 0.999f;
    float mh  = m * __builtin_amdgcn_rcpf(1.f - b1t);
    float vh  = v * __builtin_amdgcn_rcpf(1.f - b2t);
    float den = __builtin_amdgcn_sqrtf(vh) + 1e-8f;
    y -= 0.1f * mh * __builtin_amdgcn_rcpf(den);
  }

  if (lane == 0) out[i] = y;
}

// ---------------------------------------------------------------------------
extern "C" void kernel_launch(void* const* d_in, const int* in_sizes, int n_in,
                              void* d_out, int out_size, void* d_ws, size_t ws_size,
                              hipStream_t stream) {
  const float* x   = (const float*)d_in[0];
  const float* c   = (const float*)d_in[1];
  const float* hw1 = (const float*)d_in[2];
  const float* hb1 = (const float*)d_in[3];
  const float* hw2 = (const float*)d_in[4];
  const float* hb2 = (const float*)d_in[5];
  float* Pp  = (float*)d_ws;   // NCH*NB*128*4 = 159,383,552 bytes
  float* out = (float*)d_out;

  dim3 gridB(NCH, GY);         // 38 x 128 blocks
  hyper_gemm<<<gridB, dim3(256), 0, stream>>>(x, c, hw1, hb1, hw2, hb2, Pp);
  adam_inner<<<dim3(8192), dim3(64), 0, stream>>>(Pp, out);
}

// Round 15
// 198.556 us; speedup vs baseline: 7.3142x; 1.0222x over previous
//
#include <hip/hip_runtime.h>
#include <cstdint>
#include <cstddef>

// Problem constants
#define NB    8192      // batch
#define NP    4849      // params per item
#define NW    48        // target net width
#define NCH   38        // ceil(NP/128)
#define GY    64        // gemm grid y; each block does 128/GY = 2 M-tiles

// Tiled intermediate layout: addr(i, rp) = ((rp>>7)*NB + i)*128 + (rp&127)
typedef __attribute__((ext_vector_type(8))) _Float16 f16x8;
typedef __attribute__((ext_vector_type(4))) float f32x4;
typedef __attribute__((ext_vector_type(2))) float f32x2;

__device__ __forceinline__ const float* pptr(const float* Pp, int i, int rp) {
  return Pp + ((size_t)(rp >> 7) * NB + i) * 128 + (rp & 127);
}

__device__ __forceinline__ int invperm(int rp) {
  if (rp >= 96 && rp < 2400) {
    int t = rp - 96; int kb = t / 192; int rem = t - kb * 192;
    return 96 + (rem >> 2) * 48 + (kb * 4 + (rem & 3));
  }
  if (rp >= 2448 && rp < 4752) {
    int t = rp - 2448; int kb = t / 192; int rem = t - kb * 192;
    return 2448 + (rem >> 2) * 48 + (kb * 4 + (rem & 3));
  }
  return rp;
}

// ---------------------------------------------------------------------------
// Kernel 1 (FINAL = R21/R18 config): split-fp16 MFMA GEMM, GY=64.
// At the ~2.7 TB/s effective write ceiling for the 161 MB intermediate.
// Measured-neutral variants: LDS-staged coalesced epilogue (R23),
// GY=128 (R25). GY 16->64 was +10 us (R18, latency hiding).
// ---------------------------------------------------------------------------
__global__ __launch_bounds__(256, 2) void hyper_gemm(
    const float* __restrict__ x, const float* __restrict__ c,
    const float* __restrict__ hw1, const float* __restrict__ hb1,
    const float* __restrict__ hw2, const float* __restrict__ hb2,
    float* __restrict__ Pp)
{
  const int t    = threadIdx.x;
  const int lane = t & 63;
  const int wv   = t >> 6;
  const int m16  = lane & 15;
  const int q    = lane >> 4;
  const int rp0  = blockIdx.x * 128;

  const float* wr[2];
  float bias[2];
  #pragma unroll
  for (int nt = 0; nt < 2; ++nt) {
    int rp = rp0 + wv * 32 + nt * 16 + m16;
    int r  = (rp < NP) ? invperm(rp) : 0;
    wr[nt]   = hw2 + (size_t)r * 96;
    bias[nt] = (rp < NP) ? hb2[r] : 0.f;
  }

  f16x8 bh[3][2], bl[3][2];
  #pragma unroll
  for (int ch = 0; ch < 3; ++ch) {
    const int k0 = ch * 32 + q * 8;
    #pragma unroll
    for (int nt = 0; nt < 2; ++nt) {
      float4 f0 = *(const float4*)(wr[nt] + k0);
      float4 f1 = *(const float4*)(wr[nt] + k0 + 4);
      float fv[8] = {f0.x,f0.y,f0.z,f0.w,f1.x,f1.y,f1.z,f1.w};
      #pragma unroll
      for (int e = 0; e < 8; ++e) {
        _Float16 hi = (_Float16)fv[e];
        float r = fv[e] - (float)hi;
        bh[ch][nt][e] = hi;
        bl[ch][nt][e] = (_Float16)r;
      }
    }
  }

  float* cbase = Pp + (size_t)blockIdx.x * NB * 128;

  for (int mtile = blockIdx.y; mtile < 128; mtile += GY) {
    const int i0 = mtile * 64;

    float xv[4], cv[4];
    #pragma unroll
    for (int mt = 0; mt < 4; ++mt) {
      int i = i0 + mt * 16 + m16;
      xv[mt] = x[i]; cv[mt] = c[i];
    }

    f32x4 acc[4][2];
    #pragma unroll
    for (int mt = 0; mt < 4; ++mt)
      #pragma unroll
      for (int nt = 0; nt < 2; ++nt)
        acc[mt][nt] = (f32x4){0.f, 0.f, 0.f, 0.f};

    #pragma unroll
    for (int ch = 0; ch < 3; ++ch) {
      const int k0 = ch * 32 + q * 8;

      float4 A0 = *(const float4*)(hw1 + 2 * k0);
      float4 A1 = *(const float4*)(hw1 + 2 * k0 + 4);
      float4 A2 = *(const float4*)(hw1 + 2 * k0 + 8);
      float4 A3 = *(const float4*)(hw1 + 2 * k0 + 12);
      float4 B0 = *(const float4*)(hb1 + k0);
      float4 B1 = *(const float4*)(hb1 + k0 + 4);
      float w0k[8] = {A0.x,A0.z,A1.x,A1.z,A2.x,A2.z,A3.x,A3.z};
      float w1k[8] = {A0.y,A0.w,A1.y,A1.w,A2.y,A2.w,A3.y,A3.w};
      float bk[8]  = {B0.x,B0.y,B0.z,B0.w,B1.x,B1.y,B1.z,B1.w};

      f16x8 ah[4], al[4];
      #pragma unroll
      for (int mt = 0; mt < 4; ++mt) {
        #pragma unroll
        for (int j = 0; j < 8; ++j) {
          float h = fmaf(xv[mt], w0k[j], fmaf(cv[mt], w1k[j], bk[j]));
          h = h > 0.f ? h : 0.f;
          _Float16 hi = (_Float16)h;
          float r = h - (float)hi;
          ah[mt][j] = hi;
          al[mt][j] = (_Float16)r;
        }
      }

      #pragma unroll
      for (int mt = 0; mt < 4; ++mt)
        #pragma unroll
        for (int nt = 0; nt < 2; ++nt) {
          acc[mt][nt] = __builtin_amdgcn_mfma_f32_16x16x32_f16(al[mt], bl[ch][nt], acc[mt][nt], 0, 0, 0);
          acc[mt][nt] = __builtin_amdgcn_mfma_f32_16x16x32_f16(ah[mt], bl[ch][nt], acc[mt][nt], 0, 0, 0);
          acc[mt][nt] = __builtin_amdgcn_mfma_f32_16x16x32_f16(al[mt], bh[ch][nt], acc[mt][nt], 0, 0, 0);
          acc[mt][nt] = __builtin_amdgcn_mfma_f32_16x16x32_f16(ah[mt], bh[ch][nt], acc[mt][nt], 0, 0, 0);
        }
    }

    #pragma unroll
    for (int nt = 0; nt < 2; ++nt) {
      int off = wv * 32 + nt * 16 + m16;
      if (rp0 + off < NP) {
        #pragma unroll
        for (int mt = 0; mt < 4; ++mt)
          #pragma unroll
          for (int r = 0; r < 4; ++r) {
            int i = i0 + mt * 16 + q * 4 + r;
            cbase[(size_t)i * 128 + off] = acc[mt][nt][r] + bias[nt];
          }
      }
    }
  }
}

// ---------------------------------------------------------------------------
// Kernel 2 (FINAL = R21 VERBATIM; best measured 92-98.5 us, absmax 0.023).
// LDS-broadcast-bandwidth bound at ~80-85% of the DS-pipe floor (masked
// uniform ds_read_b128 @ ~8 cy each, per-CU pipe). Exec-masked b128
// broadcasts + packed f32x2 chains, __launch_bounds__(64,2).
// DO NOT set min-waves>2 with 64-thread blocks: allocator clamps VGPR to 64
// and scratch-spills (R13, R24: FETCH 1-3 GB, 3-13x slowdown).
// Measured-dead alternatives: readlane transport (R17/R20), f16 h/dh (R19
// numerics: Adam step-1 = -LR*sign(g), tiny-g sign flips), 2-item/wave
// (R22 occupancy collapse), MFMA relayout (R15/R16 correctness).
// ---------------------------------------------------------------------------

// x += dpp(x) with add-identity for invalid/masked lanes (LLVM reduce pattern)
#define DPP_ADD(x, ctrl, rmask)                                               \
  (x) += __int_as_float(__builtin_amdgcn_update_dpp(                          \
      0, __float_as_int(x), (ctrl), (rmask), 0xf, false))

__global__ __launch_bounds__(64, 2) void adam_inner(
    const float* __restrict__ Pp, float* __restrict__ out)
{
  __shared__ __align__(16) float hd[2][96];   // [buf][h(48)|dh(48)]

  const int lane = threadIdx.x;
  const int i    = blockIdx.x;
  const bool act = lane < NW;

  float* buf0 = &hd[0][0];
  float* buf1 = &hd[1][0];

  float w0  = act ? *pptr(Pp, i, lane)        : 0.f;
  float b0  = act ? *pptr(Pp, i, 48 + lane)   : 0.f;
  float b1v = act ? *pptr(Pp, i, 2400 + lane) : 0.f;
  float b2v = act ? *pptr(Pp, i, 4752 + lane) : 0.f;
  float w3  = act ? *pptr(Pp, i, 4800 + lane) : 0.f;

  f32x2 w1p[24], w2p[24];
  #pragma unroll
  for (int kb = 0; kb < 12; ++kb) {
    float4 q1 = *(const float4*)pptr(Pp, i, 96 + kb * 192 + lane * 4);
    w1p[2 * kb]     = (f32x2){q1.x, q1.y};
    w1p[2 * kb + 1] = (f32x2){q1.z, q1.w};
    float4 q2 = *(const float4*)pptr(Pp, i, 2448 + kb * 192 + lane * 4);
    w2p[2 * kb]     = (f32x2){q2.x, q2.y};
    w2p[2 * kb + 1] = (f32x2){q2.z, q2.w};
  }

  float y = 0.f, m = 0.f, v = 0.f;
  float b1t = 1.f, b2t = 1.f;

  #pragma unroll 1
  for (int t = 0; t < 20; ++t) {
    // ---- layer 0 (scalar input): lane j computes unit j ----
    float z  = fmaf(w0, y, b0);
    float s  = __builtin_amdgcn_rcpf(1.f + __expf(-z));
    float h  = z * s;
    float dh = fmaf(z * s, 1.f - s, s) * w0;
    if (act) { buf0[lane] = h; buf0[48 + lane] = dh; }

    // ---- layer 1: exec-masked broadcast prefetch, packed chains ----
    float4 ph[12], pd[12];
    if (act) {
      #pragma unroll
      for (int kk = 0; kk < 12; ++kk) {
        ph[kk] = *(const float4*)(buf0 + 4 * kk);
        pd[kk] = *(const float4*)(buf0 + 48 + 4 * kk);
      }
    }
    {
      f32x2 zz[4] = {(f32x2){b1v, 0.f}, (f32x2){0.f, 0.f},
                     (f32x2){0.f, 0.f}, (f32x2){0.f, 0.f}};
      f32x2 dd[4] = {(f32x2){0.f, 0.f}, (f32x2){0.f, 0.f},
                     (f32x2){0.f, 0.f}, (f32x2){0.f, 0.f}};
      #pragma unroll
      for (int kk = 0; kk < 12; ++kk) {
        int c0 = (2 * kk) & 3, c1 = (2 * kk + 1) & 3;
        zz[c0] = __builtin_elementwise_fma(w1p[2 * kk],     (f32x2){ph[kk].x, ph[kk].y}, zz[c0]);
        zz[c1] = __builtin_elementwise_fma(w1p[2 * kk + 1], (f32x2){ph[kk].z, ph[kk].w}, zz[c1]);
        dd[c0] = __builtin_elementwise_fma(w1p[2 * kk],     (f32x2){pd[kk].x, pd[kk].y}, dd[c0]);
        dd[c1] = __builtin_elementwise_fma(w1p[2 * kk + 1], (f32x2){pd[kk].z, pd[kk].w}, dd[c1]);
      }
      f32x2 zs = (zz[0] + zz[1]) + (zz[2] + zz[3]);
      f32x2 ds = (dd[0] + dd[1]) + (dd[2] + dd[3]);
      float z1  = zs.x + zs.y;
      float dz1 = ds.x + ds.y;

      s  = __builtin_amdgcn_rcpf(1.f + __expf(-z1));
      h  = z1 * s;
      dh = fmaf(h, 1.f - s, s) * dz1;
    }
    if (act) { buf1[lane] = h; buf1[48 + lane] = dh; }

    // ---- layer 2 ----
    if (act) {
      #pragma unroll
      for (int kk = 0; kk < 12; ++kk) {
        ph[kk] = *(const float4*)(buf1 + 4 * kk);
        pd[kk] = *(const float4*)(buf1 + 48 + 4 * kk);
      }
    }
    {
      f32x2 zz[4] = {(f32x2){b2v, 0.f}, (f32x2){0.f, 0.f},
                     (f32x2){0.f, 0.f}, (f32x2){0.f, 0.f}};
      f32x2 dd[4] = {(f32x2){0.f, 0.f}, (f32x2){0.f, 0.f},
                     (f32x2){0.f, 0.f}, (f32x2){0.f, 0.f}};
      #pragma unroll
      for (int kk = 0; kk < 12; ++kk) {
        int c0 = (2 * kk) & 3, c1 = (2 * kk + 1) & 3;
        zz[c0] = __builtin_elementwise_fma(w2p[2 * kk],     (f32x2){ph[kk].x, ph[kk].y}, zz[c0]);
        zz[c1] = __builtin_elementwise_fma(w2p[2 * kk + 1], (f32x2){ph[kk].z, ph[kk].w}, zz[c1]);
        dd[c0] = __builtin_elementwise_fma(w2p[2 * kk],     (f32x2){pd[kk].x, pd[kk].y}, dd[c0]);
        dd[c1] = __builtin_elementwise_fma(w2p[2 * kk + 1], (f32x2){pd[kk].z, pd[kk].w}, dd[c1]);
      }
      f32x2 zs = (zz[0] + zz[1]) + (zz[2] + zz[3]);
      f32x2 ds = (dd[0] + dd[1]) + (dd[2] + dd[3]);
      float z2  = zs.x + zs.y;
      float dz2 = ds.x + ds.y;

      s  = __builtin_amdgcn_rcpf(1.f + __expf(-z2));
      dh = fmaf(z2 * s, 1.f - s, s) * dz2;
    }

    // ---- g = w3 . dh3 : DPP reduction (VALU pipe, no DS ops) ----
    float r = act ? w3 * dh : 0.f;
    DPP_ADD(r, 0x111, 0xf);   // row_shr:1
    DPP_ADD(r, 0x112, 0xf);   // row_shr:2
    DPP_ADD(r, 0x114, 0xf);   // row_shr:4
    DPP_ADD(r, 0x118, 0xf);   // row_shr:8  -> lane15 of each row = row sum
    DPP_ADD(r, 0x142, 0xa);   // row_bcast:15 into rows 1,3
    DPP_ADD(r, 0x143, 0xc);   // row_bcast:31 into rows 2,3 -> lane63 = total
    float g = __int_as_float(__builtin_amdgcn_readlane(__float_as_int(r), 63));

    // ---- Adam update (replicated per lane) ----
    m = fmaf(0.9f,   m, 0.1f   * g);
    v = fmaf(0.999f, v, 0.001f * g * g);
    b1t *= 0.9f; b2t *= 0.999f;
    float mh  = m * __builtin_amdgcn_rcpf(1.f - b1t);
    float vh  = v * __builtin_amdgcn_rcpf(1.f - b2t);
    float den = __builtin_amdgcn_sqrtf(vh) + 1e-8f;
    y -= 0.1f * mh * __builtin_amdgcn_rcpf(den);
  }

  if (lane == 0) out[i] = y;
}

// ---------------------------------------------------------------------------
extern "C" void kernel_launch(void* const* d_in, const int* in_sizes, int n_in,
                              void* d_out, int out_size, void* d_ws, size_t ws_size,
                              hipStream_t stream) {
  const float* x   = (const float*)d_in[0];
  const float* c   = (const float*)d_in[1];
  const float* hw1 = (const float*)d_in[2];
  const float* hb1 = (const float*)d_in[3];
  const float* hw2 = (const float*)d_in[4];
  const float* hb2 = (const float*)d_in[5];
  float* Pp  = (float*)d_ws;   // NCH*NB*128*4 = 159,383,552 bytes
  float* out = (float*)d_out;

  dim3 gridB(NCH, GY);         // 38 x 64 blocks
  hyper_gemm<<<gridB, dim3(256), 0, stream>>>(x, c, hw1, hb1, hw2, hb2, Pp);
  adam_inner<<<dim3(8192), dim3(64), 0, stream>>>(Pp, out);
}